// Round 5
// baseline (244.430 us; speedup 1.0000x reference)
//
#include <hip/hip_runtime.h>
#include <hip/hip_fp16.h>
#include <math.h>

// ---------------- problem constants ----------------
#define NB    256
#define NTOKP 197
#define NTOK  196
#define NC    768
#define NHID  192
#define NH    14
#define NVF   8        // rfft cols = 14/2+1
#define CHT   64       // channels per tile
#define NTILE 12       // 768/64
#define HPB   4        // hiddens per block in k_mlp1

// twiddles (compile-time folded under full unroll)
constexpr float CT14[14] = {
    1.0f, 0.9009688679024191f, 0.6234898018587336f, 0.22252093395631445f,
    -0.22252093395631434f, -0.6234898018587335f, -0.9009688679024191f, -1.0f,
    -0.9009688679024191f, -0.6234898018587335f, -0.22252093395631434f,
    0.22252093395631445f, 0.6234898018587336f, 0.9009688679024191f};
constexpr float ST14[14] = {
    0.0f, 0.4338837391175581f, 0.7818314824680298f, 0.9749279121818236f,
    0.9749279121818236f, 0.7818314824680299f, 0.43388373911755823f, 0.0f,
    -0.43388373911755823f, -0.7818314824680299f, -0.9749279121818236f,
    -0.9749279121818236f, -0.7818314824680298f, -0.4338837391175581f};

__device__ __forceinline__ unsigned int pack_h2(float a, float b) {
  __half2 h = __floats2half2_rn(a, b);
  return *(unsigned int*)&h;
}
__device__ __forceinline__ float2 unpack_h2(unsigned int p) {
  __half2 h = *(__half2*)&p;
  return __half22float2(h);
}

// ---------------- K1: LayerNorm stats per (b, token) -> float2(mean, rstd) ----
__global__ __launch_bounds__(256) void k_stats(const float* __restrict__ x,
                                               float2* __restrict__ msv) {
  int row = blockIdx.x * 4 + (threadIdx.x >> 6);
  int lane = threadIdx.x & 63;
  if (row >= NB * NTOK) return;
  int b = row / NTOK, t = row - b * NTOK;
  const float4* p = (const float4*)(x + ((size_t)b * NTOKP + 1 + t) * NC);
  float s = 0.f, ss = 0.f;
#pragma unroll
  for (int k = 0; k < 3; ++k) {
    float4 v = p[lane + k * 64];
    s += v.x + v.y + v.z + v.w;
    ss += v.x * v.x + v.y * v.y + v.z * v.z + v.w * v.w;
  }
#pragma unroll
  for (int off = 32; off; off >>= 1) {
    s += __shfl_down(s, off);
    ss += __shfl_down(ss, off);
  }
  if (lane == 0) {
    float m = s * (1.f / NC);
    float var = ss * (1.f / NC) - m * m;
    msv[row] = make_float2(m, rsqrtf(var + 1e-5f));
  }
}

// ---------------- K2: forward DFT + energy (transposed out) ----------------
__global__ __launch_bounds__(256) void k_fwd(const float* __restrict__ x,
                                             const float* __restrict__ gamma,
                                             const float* __restrict__ beta,
                                             const float2* __restrict__ msv,
                                             float* __restrict__ energy_t) {
  __shared__ unsigned int A[NH * NVF * CHT];  // [i][v][c] packed fp16 (re,im) 28.7KB
  __shared__ float2 ms[NTOK];
  __shared__ float esum[256];
  int b = blockIdx.y, c0 = blockIdx.x * CHT, tid = threadIdx.x;
  int c = tid & 63, w = tid >> 6;

  for (int k = tid; k < NTOK; k += 256) ms[k] = msv[b * NTOK + k];
  float g = gamma[c0 + c], be = beta[c0 + c];
  __syncthreads();

  // stage A: per (c,i): A[i,v] = sum_j xn[i,j] e^{-2pi i v j/14}
#pragma unroll 1
  for (int i = w; i < NH; i += 4) {
    const float* xr = x + ((size_t)b * NTOKP + 1 + i * NH) * NC + c0 + c;
    float xn_[NH];
#pragma unroll
    for (int j = 0; j < NH; ++j) {
      float2 m = ms[i * NH + j];
      xn_[j] = (xr[(size_t)j * NC] - m.x) * m.y * g + be;
    }
    float ar[NVF] = {}, ai[NVF] = {};
#pragma unroll
    for (int j = 0; j < NH; ++j) {
#pragma unroll
      for (int v = 0; v < NVF; ++v) {
        ar[v] = fmaf(xn_[j], CT14[(v * j) % 14], ar[v]);
        ai[v] = fmaf(-xn_[j], ST14[(v * j) % 14], ai[v]);
      }
    }
#pragma unroll
    for (int v = 0; v < NVF; ++v) A[(i * NVF + v) * CHT + c] = pack_h2(ar[v], ai[v]);
  }
  __syncthreads();

  // stage B: per (c, v in {2w,2w+1}): S[u,v] over u=0..13, accumulate energy
  float part = 0.f;
#pragma unroll 1
  for (int vv = 0; vv < 2; ++vv) {
    int v = w * 2 + vv;
    const unsigned int* Ac = A + v * CHT + c;
    float sr[NH], si[NH];
#pragma unroll
    for (int u = 0; u < NH; ++u) { sr[u] = 0.f; si[u] = 0.f; }
#pragma unroll
    for (int i = 0; i < NH; ++i) {
      float2 a = unpack_h2(Ac[i * NVF * CHT]);
#pragma unroll
      for (int u = 0; u < NH; ++u) {
        int idx = (u * i) % 14;
        sr[u] = fmaf(a.x, CT14[idx], fmaf(a.y, ST14[idx], sr[u]));
        si[u] = fmaf(a.y, CT14[idx], fmaf(-a.x, ST14[idx], si[u]));
      }
    }
#pragma unroll
    for (int u = 0; u < NH; ++u) {
      float m2 = fmaf(sr[u], sr[u], si[u] * si[u]);
      part += __logf(1.f + __builtin_amdgcn_sqrtf(m2) * (1.f / 14.f));
    }
    if (w == 0 && vv == 0) {  // remove DC bin contribution (ref FFTs zero-mean input)
      part -= __logf(1.f + fabsf(sr[0]) * (1.f / 14.f));
    }
  }
  esum[tid] = part;
  __syncthreads();
  if (w == 0) {
    float e = esum[c] + esum[c + 64] + esum[c + 128] + esum[c + 192];
    energy_t[(size_t)(c0 + c) * NB + b] = e * (1.f / 112.f);
  }
}

// ---------------- K3a: layer 1 (batch = lane axis, coalesced) ----------------
__global__ __launch_bounds__(256) void k_mlp1(const float* __restrict__ et,
                                              const float* __restrict__ w1,
                                              const float* __restrict__ b1,
                                              float* __restrict__ hdt) {
  int h0 = blockIdx.x * HPB;
  int bb = threadIdx.x;  // batch
  float acc[HPB];
#pragma unroll
  for (int k = 0; k < HPB; ++k) acc[k] = b1[h0 + k];
  for (int cc = 0; cc < NC; ++cc) {
    float e = et[(size_t)cc * NB + bb];
#pragma unroll
    for (int k = 0; k < HPB; ++k)
      acc[k] = fmaf(e, w1[cc * NHID + h0 + k], acc[k]);
  }
#pragma unroll
  for (int k = 0; k < HPB; ++k) {
    float a = acc[k];
    float ge = 0.5f * a * (1.f + erff(a * 0.70710678118654752f));  // exact gelu
    hdt[(size_t)(h0 + k) * NB + bb] = ge;
  }
}

// ---------------- K3b: layer 2 + mask params ----------------
__global__ __launch_bounds__(256) void k_mlp2(const float* __restrict__ hdt,
                                              const float* __restrict__ w2,
                                              const float* __restrict__ b2,
                                              float* __restrict__ m2s) {
  int bb = threadIdx.x;
  float a0 = b2[0], a1 = b2[1];
  for (int h = 0; h < NHID; ++h) {
    float hv = hdt[(size_t)h * NB + bb];
    a0 = fmaf(hv, w2[2 * h], a0);
    a1 = fmaf(hv, w2[2 * h + 1], a1);
  }
  float muv = 9.899494936611665f / (1.f + expf(-a0));
  muv = fmaxf(muv, 1.f);
  float sp = (a1 > 20.f) ? a1 : log1pf(expf(a1));
  float sg = fmaxf(sp, 0.1f);
  m2s[bb] = 2.f * muv * muv * sg + 1e-6f;
}

// ---------------- K4: separable circulant filter + residual ----------------
// mask separable: exp(-(fy2[u]+fx2[v])/ms) = wexp[u]*wexp[v]
// filtered = K (x) K (x) xn  (mean path drops out: mask[0,0]=1 => K*const=const)
__global__ __launch_bounds__(256) void k_inv(const float* __restrict__ x,
                                             const float* __restrict__ gamma,
                                             const float* __restrict__ beta,
                                             const float2* __restrict__ msv,
                                             const float* __restrict__ m2s,
                                             const float* __restrict__ rscale,
                                             float* __restrict__ out) {
  __shared__ unsigned int T[NH * 7 * CHT];  // y[i][j'] fp16 pairs: 25KB
  __shared__ float2 ms[NTOK];
  __shared__ float wexp[NH];
  __shared__ float kc[NH];
  int b = blockIdx.y, c0 = blockIdx.x * CHT, tid = threadIdx.x;
  int c = tid & 63, w = tid >> 6;
  float rs = rscale[0];

  for (int k = tid; k < NTOK; k += 256) ms[k] = msv[b * NTOK + k];
  if (tid < CHT) {  // cls-token passthrough
    size_t idx = (size_t)b * NTOKP * NC + c0 + tid;
    out[idx] = x[idx];
  }
  float msb = m2s[b];
  if (tid < NH) {
    int f = (tid <= 7) ? tid : 14 - tid;
    wexp[tid] = __expf(-(float)(f * f) / msb);
  }
  __syncthreads();
  if (tid < NH) {
    float s = 0.f;
#pragma unroll
    for (int k = 0; k < NH; ++k) s = fmaf(wexp[k], CT14[(k * tid) % 14], s);
    kc[tid] = s * (1.f / 14.f);
  }
  float g = gamma[c0 + c], be = beta[c0 + c];
  __syncthreads();

  float kr[NH];
#pragma unroll
  for (int d = 0; d < NH; ++d) kr[d] = kc[d];

  // stage 1: per (c,i): y[i,j'] = sum_j xn[i,j]*kc[(j'-j)%14] -> T
#pragma unroll 1
  for (int i = w; i < NH; i += 4) {
    const float* xr = x + ((size_t)b * NTOKP + 1 + i * NH) * NC + c0 + c;
    float xn_[NH];
#pragma unroll
    for (int j = 0; j < NH; ++j) {
      float2 m = ms[i * NH + j];
      xn_[j] = (xr[(size_t)j * NC] - m.x) * m.y * g + be;
    }
#pragma unroll
    for (int jp = 0; jp < 7; ++jp) {
      float y0 = 0.f, y1 = 0.f;
#pragma unroll
      for (int j = 0; j < NH; ++j) {
        y0 = fmaf(xn_[j], kr[(2 * jp - j + 28) % 14], y0);
        y1 = fmaf(xn_[j], kr[(2 * jp + 1 - j + 28) % 14], y1);
      }
      T[(i * 7 + jp) * CHT + c] = pack_h2(y0, y1);
    }
  }
  __syncthreads();

  // stage 2: per (c,jq): z[i'] = sum_i y[i,jq]*kc[(i'-i)%14]; out = xv + rs*(z-xn)
#pragma unroll 1
  for (int jq = w; jq < NH; jq += 4) {
    int jp = jq >> 1, hi = jq & 1;
    float y[NH];
#pragma unroll
    for (int i = 0; i < NH; ++i) {
      float2 v = unpack_h2(T[(i * 7 + jp) * CHT + c]);
      y[i] = hi ? v.y : v.x;
    }
    const float* xr = x + ((size_t)b * NTOKP + 1 + jq) * NC + c0 + c;
    float* outr = out + ((size_t)b * NTOKP + 1 + jq) * NC + c0 + c;
#pragma unroll
    for (int ii = 0; ii < NH; ++ii) {
      float z = 0.f;
#pragma unroll
      for (int i = 0; i < NH; ++i) z = fmaf(y[i], kr[(ii - i + 28) % 14], z);
      float xv = xr[(size_t)ii * NH * NC];
      float2 m = ms[ii * NH + jq];
      float xn = (xv - m.x) * m.y * g + be;
      outr[(size_t)ii * NH * NC] = xv + rs * (z - xn);
    }
  }
}

extern "C" void kernel_launch(void* const* d_in, const int* in_sizes, int n_in,
                              void* d_out, int out_size, void* d_ws, size_t ws_size,
                              hipStream_t stream) {
  (void)in_sizes; (void)n_in; (void)out_size; (void)ws_size;
  const float* x      = (const float*)d_in[0];
  const float* gamma  = (const float*)d_in[1];
  const float* beta   = (const float*)d_in[2];
  const float* w1     = (const float*)d_in[3];
  const float* b1     = (const float*)d_in[4];
  const float* w2     = (const float*)d_in[5];
  const float* b2     = (const float*)d_in[6];
  const float* rscale = (const float*)d_in[7];
  float* out = (float*)d_out;

  char* wsb = (char*)d_ws;
  float2* msv     = (float2*)(wsb + 0);        //   401,408 B
  float* energy_t = (float*)(wsb + 401408);    //   786,432 B  [NC][NB]
  float* hdt      = (float*)(wsb + 1187840);   //   196,608 B  [NHID][NB]
  float* m2s      = (float*)(wsb + 1384448);   //     1,024 B

  k_stats<<<(NB * NTOK + 3) / 4, 256, 0, stream>>>(x, msv);
  k_fwd<<<dim3(NTILE, NB), 256, 0, stream>>>(x, gamma, beta, msv, energy_t);
  k_mlp1<<<NHID / HPB, 256, 0, stream>>>(energy_t, w1, b1, hdt);
  k_mlp2<<<1, 256, 0, stream>>>(hdt, w2, b2, m2s);
  k_inv<<<dim3(NTILE, NB), 256, 0, stream>>>(x, gamma, beta, msv, m2s, rscale,
                                             out);
}

// Round 6
// 198.491 us; speedup vs baseline: 1.2314x; 1.2314x over previous
//
#include <hip/hip_runtime.h>
#include <hip/hip_fp16.h>
#include <math.h>

// ---------------- problem constants ----------------
#define NB    256
#define NTOKP 197
#define NTOK  196
#define NC    768
#define NHID  192
#define NH    14
#define NVF   8        // rfft cols = 14/2+1
#define CHT   64       // channels per tile
#define NTILE 12       // 768/64

// twiddles (compile-time folded under full unroll)
constexpr float CT14[14] = {
    1.0f, 0.9009688679024191f, 0.6234898018587336f, 0.22252093395631445f,
    -0.22252093395631434f, -0.6234898018587335f, -0.9009688679024191f, -1.0f,
    -0.9009688679024191f, -0.6234898018587335f, -0.22252093395631434f,
    0.22252093395631445f, 0.6234898018587336f, 0.9009688679024191f};
constexpr float ST14[14] = {
    0.0f, 0.4338837391175581f, 0.7818314824680298f, 0.9749279121818236f,
    0.9749279121818236f, 0.7818314824680299f, 0.43388373911755823f, 0.0f,
    -0.43388373911755823f, -0.7818314824680299f, -0.9749279121818236f,
    -0.9749279121818236f, -0.7818314824680298f, -0.4338837391175581f};

__device__ __forceinline__ unsigned int pack_h2(float a, float b) {
  __half2 h = __floats2half2_rn(a, b);
  return *(unsigned int*)&h;
}
__device__ __forceinline__ float2 unpack_h2(unsigned int p) {
  __half2 h = *(__half2*)&p;
  return __half22float2(h);
}

// ---------------- K1: LayerNorm stats per (b, token) -> float2(mean, rstd) ----
__global__ __launch_bounds__(256) void k_stats(const float* __restrict__ x,
                                               float2* __restrict__ msv) {
  int row = blockIdx.x * 4 + (threadIdx.x >> 6);
  int lane = threadIdx.x & 63;
  if (row >= NB * NTOK) return;
  int b = row / NTOK, t = row - b * NTOK;
  const float4* p = (const float4*)(x + ((size_t)b * NTOKP + 1 + t) * NC);
  float s = 0.f, ss = 0.f;
#pragma unroll
  for (int k = 0; k < 3; ++k) {
    float4 v = p[lane + k * 64];
    s += v.x + v.y + v.z + v.w;
    ss += v.x * v.x + v.y * v.y + v.z * v.z + v.w * v.w;
  }
#pragma unroll
  for (int off = 32; off; off >>= 1) {
    s += __shfl_down(s, off);
    ss += __shfl_down(ss, off);
  }
  if (lane == 0) {
    float m = s * (1.f / NC);
    float var = ss * (1.f / NC) - m * m;
    msv[row] = make_float2(m, rsqrtf(var + 1e-5f));
  }
}

// ---------------- K2: forward DFT + energy (transposed out) ----------------
__global__ __launch_bounds__(256) void k_fwd(const float* __restrict__ x,
                                             const float* __restrict__ gamma,
                                             const float* __restrict__ beta,
                                             const float2* __restrict__ msv,
                                             float* __restrict__ energy_t) {
  __shared__ unsigned int A[NH * NVF * CHT];  // [i][v][c] packed fp16 (re,im) 28.7KB
  __shared__ float2 ms[NTOK];
  __shared__ float esum[256];
  int b = blockIdx.y, c0 = blockIdx.x * CHT, tid = threadIdx.x;
  int c = tid & 63, w = tid >> 6;

  for (int k = tid; k < NTOK; k += 256) ms[k] = msv[b * NTOK + k];
  float g = gamma[c0 + c], be = beta[c0 + c];
  __syncthreads();

  // stage A: per (c,i): A[i,v] = sum_j xn[i,j] e^{-2pi i v j/14}
#pragma unroll 1
  for (int i = w; i < NH; i += 4) {
    const float* xr = x + ((size_t)b * NTOKP + 1 + i * NH) * NC + c0 + c;
    float xn_[NH];
#pragma unroll
    for (int j = 0; j < NH; ++j) {
      float2 m = ms[i * NH + j];
      xn_[j] = (xr[(size_t)j * NC] - m.x) * m.y * g + be;
    }
    float ar[NVF] = {}, ai[NVF] = {};
#pragma unroll
    for (int j = 0; j < NH; ++j) {
#pragma unroll
      for (int v = 0; v < NVF; ++v) {
        ar[v] = fmaf(xn_[j], CT14[(v * j) % 14], ar[v]);
        ai[v] = fmaf(-xn_[j], ST14[(v * j) % 14], ai[v]);
      }
    }
#pragma unroll
    for (int v = 0; v < NVF; ++v) A[(i * NVF + v) * CHT + c] = pack_h2(ar[v], ai[v]);
  }
  __syncthreads();

  // stage B: per (c, v in {2w,2w+1}): S[u,v] over u=0..13, accumulate energy
  float part = 0.f;
#pragma unroll 1
  for (int vv = 0; vv < 2; ++vv) {
    int v = w * 2 + vv;
    const unsigned int* Ac = A + v * CHT + c;
    float sr[NH], si[NH];
#pragma unroll
    for (int u = 0; u < NH; ++u) { sr[u] = 0.f; si[u] = 0.f; }
#pragma unroll
    for (int i = 0; i < NH; ++i) {
      float2 a = unpack_h2(Ac[i * NVF * CHT]);
#pragma unroll
      for (int u = 0; u < NH; ++u) {
        int idx = (u * i) % 14;
        sr[u] = fmaf(a.x, CT14[idx], fmaf(a.y, ST14[idx], sr[u]));
        si[u] = fmaf(a.y, CT14[idx], fmaf(-a.x, ST14[idx], si[u]));
      }
    }
#pragma unroll
    for (int u = 0; u < NH; ++u) {
      float m2 = fmaf(sr[u], sr[u], si[u] * si[u]);
      part += __logf(1.f + __builtin_amdgcn_sqrtf(m2) * (1.f / 14.f));
    }
    if (w == 0 && vv == 0) {  // remove DC bin contribution (ref FFTs zero-mean input)
      part -= __logf(1.f + fabsf(sr[0]) * (1.f / 14.f));
    }
  }
  esum[tid] = part;
  __syncthreads();
  if (w == 0) {
    float e = esum[c] + esum[c + 64] + esum[c + 128] + esum[c + 192];
    energy_t[(size_t)(c0 + c) * NB + b] = e * (1.f / 112.f);
  }
}

// ---------------- K3a: layer 1. One hidden per block, 512 thr (split-K x2) ----
__global__ __launch_bounds__(512) void k_mlp1(const float* __restrict__ et,
                                              const float* __restrict__ w1,
                                              const float* __restrict__ b1,
                                              float* __restrict__ hdt) {
  __shared__ float part[NB];
  int h = blockIdx.x;
  int t = threadIdx.x;
  int bb = t & 255, half = t >> 8;
  const float* ec = et + (size_t)(half * 384) * NB + bb;   // coalesced across bb
  const float* wc = w1 + (size_t)(half * 384) * NHID + h;  // wave-uniform (s_load)
  float acc = 0.f;
#pragma unroll 8
  for (int cc = 0; cc < 384; ++cc)
    acc = fmaf(ec[(size_t)cc * NB], wc[(size_t)cc * NHID], acc);
  if (half) part[bb] = acc;
  __syncthreads();
  if (!half) {
    float a = acc + part[bb] + b1[h];
    float ge = 0.5f * a * (1.f + erff(a * 0.70710678118654752f));  // exact gelu
    hdt[(size_t)h * NB + bb] = ge;
  }
}

// ---------------- K3b: layer 2 + mask params ----------------
__global__ __launch_bounds__(256) void k_mlp2(const float* __restrict__ hdt,
                                              const float* __restrict__ w2,
                                              const float* __restrict__ b2,
                                              float* __restrict__ m2s) {
  int bb = threadIdx.x;
  float a0 = b2[0], a1 = b2[1];
#pragma unroll 8
  for (int h = 0; h < NHID; ++h) {
    float hv = hdt[(size_t)h * NB + bb];
    a0 = fmaf(hv, w2[2 * h], a0);
    a1 = fmaf(hv, w2[2 * h + 1], a1);
  }
  float muv = 9.899494936611665f / (1.f + expf(-a0));
  muv = fmaxf(muv, 1.f);
  float sp = (a1 > 20.f) ? a1 : log1pf(expf(a1));
  float sg = fmaxf(sp, 0.1f);
  m2s[bb] = 2.f * muv * muv * sg + 1e-6f;
}

// ---------------- K4: separable circulant filter + residual ----------------
// mask separable: exp(-(fy2[u]+fx2[v])/ms) = wexp[u]*wexp[v]
// filtered = K (x) K (x) xn  (mean path drops out: mask[0,0]=1 => K*const=const)
__global__ __launch_bounds__(256) void k_inv(const float* __restrict__ x,
                                             const float* __restrict__ gamma,
                                             const float* __restrict__ beta,
                                             const float2* __restrict__ msv,
                                             const float* __restrict__ m2s,
                                             const float* __restrict__ rscale,
                                             float* __restrict__ out) {
  __shared__ unsigned int T[NH * 7 * CHT];  // y[i][j'] fp16 pairs: 25KB
  __shared__ float2 ms[NTOK];
  __shared__ float wexp[NH];
  __shared__ float kc[NH];
  int b = blockIdx.y, c0 = blockIdx.x * CHT, tid = threadIdx.x;
  int c = tid & 63, w = tid >> 6;
  float rs = rscale[0];

  for (int k = tid; k < NTOK; k += 256) ms[k] = msv[b * NTOK + k];
  if (tid < CHT) {  // cls-token passthrough
    size_t idx = (size_t)b * NTOKP * NC + c0 + tid;
    out[idx] = x[idx];
  }
  float msb = m2s[b];
  if (tid < NH) {
    int f = (tid <= 7) ? tid : 14 - tid;
    wexp[tid] = __expf(-(float)(f * f) / msb);
  }
  __syncthreads();
  if (tid < NH) {
    float s = 0.f;
#pragma unroll
    for (int k = 0; k < NH; ++k) s = fmaf(wexp[k], CT14[(k * tid) % 14], s);
    kc[tid] = s * (1.f / 14.f);
  }
  float g = gamma[c0 + c], be = beta[c0 + c];
  __syncthreads();

  float kr[NH];
#pragma unroll
  for (int d = 0; d < NH; ++d) kr[d] = kc[d];

  // stage 1: per (c,i): y[i,j'] = sum_j xn[i,j]*kc[(j'-j)%14] -> T
#pragma unroll 1
  for (int i = w; i < NH; i += 4) {
    const float* xr = x + ((size_t)b * NTOKP + 1 + i * NH) * NC + c0 + c;
    float xn_[NH];
#pragma unroll
    for (int j = 0; j < NH; ++j) {
      float2 m = ms[i * NH + j];
      xn_[j] = (xr[(size_t)j * NC] - m.x) * m.y * g + be;
    }
#pragma unroll
    for (int jp = 0; jp < 7; ++jp) {
      float y0 = 0.f, y1 = 0.f;
#pragma unroll
      for (int j = 0; j < NH; ++j) {
        y0 = fmaf(xn_[j], kr[(2 * jp - j + 28) % 14], y0);
        y1 = fmaf(xn_[j], kr[(2 * jp + 1 - j + 28) % 14], y1);
      }
      T[(i * 7 + jp) * CHT + c] = pack_h2(y0, y1);
    }
  }
  __syncthreads();

  // stage 2: per (c,jq): z[i'] = sum_i y[i,jq]*kc[(i'-i)%14]; out = xv + rs*(z-xn)
#pragma unroll 1
  for (int jq = w; jq < NH; jq += 4) {
    int jp = jq >> 1, hi = jq & 1;
    float y[NH];
#pragma unroll
    for (int i = 0; i < NH; ++i) {
      float2 v = unpack_h2(T[(i * 7 + jp) * CHT + c]);
      y[i] = hi ? v.y : v.x;
    }
    const float* xr = x + ((size_t)b * NTOKP + 1 + jq) * NC + c0 + c;
    float* outr = out + ((size_t)b * NTOKP + 1 + jq) * NC + c0 + c;
#pragma unroll
    for (int ii = 0; ii < NH; ++ii) {
      float z = 0.f;
#pragma unroll
      for (int i = 0; i < NH; ++i) z = fmaf(y[i], kr[(ii - i + 28) % 14], z);
      float xv = xr[(size_t)ii * NH * NC];
      float2 m = ms[ii * NH + jq];
      float xn = (xv - m.x) * m.y * g + be;
      outr[(size_t)ii * NH * NC] = xv + rs * (z - xn);
    }
  }
}

extern "C" void kernel_launch(void* const* d_in, const int* in_sizes, int n_in,
                              void* d_out, int out_size, void* d_ws, size_t ws_size,
                              hipStream_t stream) {
  (void)in_sizes; (void)n_in; (void)out_size; (void)ws_size;
  const float* x      = (const float*)d_in[0];
  const float* gamma  = (const float*)d_in[1];
  const float* beta   = (const float*)d_in[2];
  const float* w1     = (const float*)d_in[3];
  const float* b1     = (const float*)d_in[4];
  const float* w2     = (const float*)d_in[5];
  const float* b2     = (const float*)d_in[6];
  const float* rscale = (const float*)d_in[7];
  float* out = (float*)d_out;

  char* wsb = (char*)d_ws;
  float2* msv     = (float2*)(wsb + 0);        //   401,408 B
  float* energy_t = (float*)(wsb + 401408);    //   786,432 B  [NC][NB]
  float* hdt      = (float*)(wsb + 1187840);   //   196,608 B  [NHID][NB]
  float* m2s      = (float*)(wsb + 1384448);   //     1,024 B

  k_stats<<<(NB * NTOK + 3) / 4, 256, 0, stream>>>(x, msv);
  k_fwd<<<dim3(NTILE, NB), 256, 0, stream>>>(x, gamma, beta, msv, energy_t);
  k_mlp1<<<NHID, 512, 0, stream>>>(energy_t, w1, b1, hdt);
  k_mlp2<<<1, 256, 0, stream>>>(hdt, w2, b2, m2s);
  k_inv<<<dim3(NTILE, NB), 256, 0, stream>>>(x, gamma, beta, msv, m2s, rscale,
                                             out);
}

// Round 7
// 190.564 us; speedup vs baseline: 1.2827x; 1.0416x over previous
//
#include <hip/hip_runtime.h>
#include <hip/hip_fp16.h>
#include <math.h>

// ---------------- problem constants ----------------
#define NB    256
#define NTOKP 197
#define NTOK  196
#define NC    768
#define NHID  192
#define NH    14
#define NVF   8        // rfft cols = 14/2+1
#define CHT   64       // channels per tile
#define NTILE 12       // 768/64

// twiddles (compile-time folded under full unroll)
constexpr float CT14[14] = {
    1.0f, 0.9009688679024191f, 0.6234898018587336f, 0.22252093395631445f,
    -0.22252093395631434f, -0.6234898018587335f, -0.9009688679024191f, -1.0f,
    -0.9009688679024191f, -0.6234898018587335f, -0.22252093395631434f,
    0.22252093395631445f, 0.6234898018587336f, 0.9009688679024191f};
constexpr float ST14[14] = {
    0.0f, 0.4338837391175581f, 0.7818314824680298f, 0.9749279121818236f,
    0.9749279121818236f, 0.7818314824680299f, 0.43388373911755823f, 0.0f,
    -0.43388373911755823f, -0.7818314824680299f, -0.9749279121818236f,
    -0.9749279121818236f, -0.7818314824680298f, -0.4338837391175581f};

__device__ __forceinline__ unsigned int pack_h2(float a, float b) {
  __half2 h = __floats2half2_rn(a, b);
  return *(unsigned int*)&h;
}
__device__ __forceinline__ float2 unpack_h2(unsigned int p) {
  __half2 h = *(__half2*)&p;
  return __half22float2(h);
}

// ---------------- K1: LayerNorm stats per (b, token) -> float2(mean, rstd) ----
__global__ __launch_bounds__(256) void k_stats(const float* __restrict__ x,
                                               float2* __restrict__ msv) {
  int row = blockIdx.x * 4 + (threadIdx.x >> 6);
  int lane = threadIdx.x & 63;
  if (row >= NB * NTOK) return;
  int b = row / NTOK, t = row - b * NTOK;
  const float4* p = (const float4*)(x + ((size_t)b * NTOKP + 1 + t) * NC);
  float s = 0.f, ss = 0.f;
#pragma unroll
  for (int k = 0; k < 3; ++k) {
    float4 v = p[lane + k * 64];
    s += v.x + v.y + v.z + v.w;
    ss += v.x * v.x + v.y * v.y + v.z * v.z + v.w * v.w;
  }
#pragma unroll
  for (int off = 32; off; off >>= 1) {
    s += __shfl_down(s, off);
    ss += __shfl_down(ss, off);
  }
  if (lane == 0) {
    float m = s * (1.f / NC);
    float var = ss * (1.f / NC) - m * m;
    msv[row] = make_float2(m, rsqrtf(var + 1e-5f));
  }
}

// ---------------- K2: forward DFT + energy ----------------
__global__ __launch_bounds__(256) void k_fwd(const float* __restrict__ x,
                                             const float* __restrict__ gamma,
                                             const float* __restrict__ beta,
                                             const float2* __restrict__ msv,
                                             float* __restrict__ energy) {
  __shared__ unsigned int A[NH * NVF * CHT];  // [i][v][c] packed fp16 (re,im) 28.7KB
  __shared__ float2 ms[NTOK];
  __shared__ float esum[256];
  int b = blockIdx.y, c0 = blockIdx.x * CHT, tid = threadIdx.x;
  int c = tid & 63, w = tid >> 6;

  for (int k = tid; k < NTOK; k += 256) ms[k] = msv[b * NTOK + k];
  float g = gamma[c0 + c], be = beta[c0 + c];
  __syncthreads();

  // stage A: per (c,i): A[i,v] = sum_j xn[i,j] e^{-2pi i v j/14}
#pragma unroll 1
  for (int i = w; i < NH; i += 4) {
    const float* xr = x + ((size_t)b * NTOKP + 1 + i * NH) * NC + c0 + c;
    float xn_[NH];
#pragma unroll
    for (int j = 0; j < NH; ++j) {
      float2 m = ms[i * NH + j];
      xn_[j] = (xr[(size_t)j * NC] - m.x) * m.y * g + be;
    }
    float ar[NVF] = {}, ai[NVF] = {};
#pragma unroll
    for (int j = 0; j < NH; ++j) {
#pragma unroll
      for (int v = 0; v < NVF; ++v) {
        ar[v] = fmaf(xn_[j], CT14[(v * j) % 14], ar[v]);
        ai[v] = fmaf(-xn_[j], ST14[(v * j) % 14], ai[v]);
      }
    }
#pragma unroll
    for (int v = 0; v < NVF; ++v) A[(i * NVF + v) * CHT + c] = pack_h2(ar[v], ai[v]);
  }
  __syncthreads();

  // stage B: per (c, v in {2w,2w+1}): S[u,v] over u=0..13, accumulate energy
  float part = 0.f;
#pragma unroll 1
  for (int vv = 0; vv < 2; ++vv) {
    int v = w * 2 + vv;
    const unsigned int* Ac = A + v * CHT + c;
    float sr[NH], si[NH];
#pragma unroll
    for (int u = 0; u < NH; ++u) { sr[u] = 0.f; si[u] = 0.f; }
#pragma unroll
    for (int i = 0; i < NH; ++i) {
      float2 a = unpack_h2(Ac[i * NVF * CHT]);
#pragma unroll
      for (int u = 0; u < NH; ++u) {
        int idx = (u * i) % 14;
        sr[u] = fmaf(a.x, CT14[idx], fmaf(a.y, ST14[idx], sr[u]));
        si[u] = fmaf(a.y, CT14[idx], fmaf(-a.x, ST14[idx], si[u]));
      }
    }
#pragma unroll
    for (int u = 0; u < NH; ++u) {
      float m2 = fmaf(sr[u], sr[u], si[u] * si[u]);
      part += __logf(1.f + __builtin_amdgcn_sqrtf(m2) * (1.f / 14.f));
    }
    if (w == 0 && vv == 0) {  // remove DC bin contribution (ref FFTs zero-mean input)
      part -= __logf(1.f + fabsf(sr[0]) * (1.f / 14.f));
    }
  }
  esum[tid] = part;
  __syncthreads();
  if (w == 0) {
    float e = esum[c] + esum[c + 64] + esum[c + 128] + esum[c + 192];
    energy[(size_t)b * NC + c0 + c] = e * (1.f / 112.f);
  }
}

// ---------------- K3: fused MLP (both layers) per batch ----------------
__global__ __launch_bounds__(256) void k_mlp(const float* __restrict__ energy,
                                             const float* __restrict__ w1,
                                             const float* __restrict__ b1,
                                             const float* __restrict__ w2,
                                             const float* __restrict__ b2,
                                             float* __restrict__ m2s) {
  __shared__ float e[NC];
  __shared__ float hd[NHID];
  int b = blockIdx.x, tid = threadIdx.x;
#pragma unroll
  for (int k = 0; k < 3; ++k) e[tid + k * 256] = energy[(size_t)b * NC + tid + k * 256];
  __syncthreads();
  if (tid < NHID) {
    // 8 independent accumulator chains; 8 loads in flight per group
    float acc[8] = {};
#pragma unroll 1
    for (int cc = 0; cc < NC; cc += 8) {
#pragma unroll
      for (int k = 0; k < 8; ++k)
        acc[k] = fmaf(e[cc + k], w1[(size_t)(cc + k) * NHID + tid], acc[k]);
    }
    float a = ((acc[0] + acc[1]) + (acc[2] + acc[3])) +
              ((acc[4] + acc[5]) + (acc[6] + acc[7])) + b1[tid];
    hd[tid] = 0.5f * a * (1.f + erff(a * 0.70710678118654752f));  // exact gelu
  }
  __syncthreads();
  if (tid < 64) {
    float p0 = 0.f, p1 = 0.f;
#pragma unroll
    for (int k = 0; k < 3; ++k) {
      float hv = hd[tid + k * 64];
      p0 = fmaf(hv, w2[2 * (tid + k * 64)], p0);
      p1 = fmaf(hv, w2[2 * (tid + k * 64) + 1], p1);
    }
#pragma unroll
    for (int off = 32; off; off >>= 1) {
      p0 += __shfl_down(p0, off);
      p1 += __shfl_down(p1, off);
    }
    if (tid == 0) {
      float o0 = p0 + b2[0], o1 = p1 + b2[1];
      float muv = 9.899494936611665f / (1.f + expf(-o0));
      muv = fmaxf(muv, 1.f);
      float sp = (o1 > 20.f) ? o1 : log1pf(expf(o1));
      float sg = fmaxf(sp, 0.1f);
      m2s[b] = 2.f * muv * muv * sg + 1e-6f;
    }
  }
}

// ---------------- K4: separable circulant filter + residual ----------------
// mask separable: exp(-(fy2[u]+fx2[v])/ms) = wexp[u]*wexp[v]
// filtered = K (x) K (x) xn  (mean path drops out: mask[0,0]=1 => K*const=const)
__global__ __launch_bounds__(256) void k_inv(const float* __restrict__ x,
                                             const float* __restrict__ gamma,
                                             const float* __restrict__ beta,
                                             const float2* __restrict__ msv,
                                             const float* __restrict__ m2s,
                                             const float* __restrict__ rscale,
                                             float* __restrict__ out) {
  __shared__ unsigned int T[NH * 7 * CHT];  // y[i][j'] fp16 pairs: 25KB
  __shared__ float2 ms[NTOK];
  __shared__ float wexp[NH];
  __shared__ float kc[NH];
  int b = blockIdx.y, c0 = blockIdx.x * CHT, tid = threadIdx.x;
  int c = tid & 63, w = tid >> 6;
  float rs = rscale[0];

  for (int k = tid; k < NTOK; k += 256) ms[k] = msv[b * NTOK + k];
  if (tid < CHT) {  // cls-token passthrough
    size_t idx = (size_t)b * NTOKP * NC + c0 + tid;
    out[idx] = x[idx];
  }
  float msb = m2s[b];
  if (tid < NH) {
    int f = (tid <= 7) ? tid : 14 - tid;
    wexp[tid] = __expf(-(float)(f * f) / msb);
  }
  __syncthreads();
  if (tid < NH) {
    float s = 0.f;
#pragma unroll
    for (int k = 0; k < NH; ++k) s = fmaf(wexp[k], CT14[(k * tid) % 14], s);
    kc[tid] = s * (1.f / 14.f);
  }
  float g = gamma[c0 + c], be = beta[c0 + c];
  __syncthreads();

  float kr[NH];
#pragma unroll
  for (int d = 0; d < NH; ++d) kr[d] = kc[d];

  // stage 1: per (c,i): y[i,j'] = sum_j xn[i,j]*kc[(j'-j)%14] -> T
#pragma unroll 1
  for (int i = w; i < NH; i += 4) {
    const float* xr = x + ((size_t)b * NTOKP + 1 + i * NH) * NC + c0 + c;
    float xn_[NH];
#pragma unroll
    for (int j = 0; j < NH; ++j) {
      float2 m = ms[i * NH + j];
      xn_[j] = (xr[(size_t)j * NC] - m.x) * m.y * g + be;
    }
#pragma unroll
    for (int jp = 0; jp < 7; ++jp) {
      float y0 = 0.f, y1 = 0.f;
#pragma unroll
      for (int j = 0; j < NH; ++j) {
        y0 = fmaf(xn_[j], kr[(2 * jp - j + 28) % 14], y0);
        y1 = fmaf(xn_[j], kr[(2 * jp + 1 - j + 28) % 14], y1);
      }
      T[(i * 7 + jp) * CHT + c] = pack_h2(y0, y1);
    }
  }
  __syncthreads();

  // stage 2: per (c,jq): z[i'] = sum_i y[i,jq]*kc[(i'-i)%14]; out = xv + rs*(z-xn)
#pragma unroll 1
  for (int jq = w; jq < NH; jq += 4) {
    int jp = jq >> 1, hi = jq & 1;
    float y[NH];
#pragma unroll
    for (int i = 0; i < NH; ++i) {
      float2 v = unpack_h2(T[(i * 7 + jp) * CHT + c]);
      y[i] = hi ? v.y : v.x;
    }
    const float* xr = x + ((size_t)b * NTOKP + 1 + jq) * NC + c0 + c;
    float* outr = out + ((size_t)b * NTOKP + 1 + jq) * NC + c0 + c;
#pragma unroll
    for (int ii = 0; ii < NH; ++ii) {
      float z = 0.f;
#pragma unroll
      for (int i = 0; i < NH; ++i) z = fmaf(y[i], kr[(ii - i + 28) % 14], z);
      float xv = xr[(size_t)ii * NH * NC];
      float2 m = ms[ii * NH + jq];
      float xn = (xv - m.x) * m.y * g + be;
      outr[(size_t)ii * NH * NC] = xv + rs * (z - xn);
    }
  }
}

extern "C" void kernel_launch(void* const* d_in, const int* in_sizes, int n_in,
                              void* d_out, int out_size, void* d_ws, size_t ws_size,
                              hipStream_t stream) {
  (void)in_sizes; (void)n_in; (void)out_size; (void)ws_size;
  const float* x      = (const float*)d_in[0];
  const float* gamma  = (const float*)d_in[1];
  const float* beta   = (const float*)d_in[2];
  const float* w1     = (const float*)d_in[3];
  const float* b1     = (const float*)d_in[4];
  const float* w2     = (const float*)d_in[5];
  const float* b2     = (const float*)d_in[6];
  const float* rscale = (const float*)d_in[7];
  float* out = (float*)d_out;

  char* wsb = (char*)d_ws;
  float2* msv   = (float2*)(wsb + 0);        //   401,408 B
  float* energy = (float*)(wsb + 401408);    //   786,432 B  [NB][NC]
  float* m2s    = (float*)(wsb + 1187840);   //     1,024 B

  k_stats<<<(NB * NTOK + 3) / 4, 256, 0, stream>>>(x, msv);
  k_fwd<<<dim3(NTILE, NB), 256, 0, stream>>>(x, gamma, beta, msv, energy);
  k_mlp<<<NB, 256, 0, stream>>>(energy, w1, b1, w2, b2, m2s);
  k_inv<<<dim3(NTILE, NB), 256, 0, stream>>>(x, gamma, beta, msv, m2s, rscale,
                                             out);
}